// Round 9
// baseline (298.200 us; speedup 1.0000x reference)
//
#include <hip/hip_runtime.h>

#define K_CODES 4096
#define D 256
#define N_VEC 32768
#define N_ELEM 8388608   // 32*256*32*32
#define WINDOW 3.5e-4f
#define WINDOW_C 5.25e-4f  // certify capture window (1.5x WINDOW > W margin)
#define CAP 14             // candidate capacity per position (certify)
#define CSTRIDE 16         // u16 slots per position in candl
#define RG 8               // rescan positions per group (fallback)
#define RSLICE 256         // rescan codes per slice (fallback)

typedef _Float16 f16x8 __attribute__((ext_vector_type(8)));
typedef float f32x4 __attribute__((ext_vector_type(4)));

// ws layout (bytes)
#define WS_LOSS 0
#define WS_COUNT 8
#define WS_DONE 16
#define WS_COUNT2 24
#define WS_IDX 256
#define WS_LIST (WS_IDX + N_VEC * 4)
#define WS_ESQ (WS_LIST + N_VEC * 4)
#define WS_ZSQ (WS_ESQ + K_CODES * 4)
#define WS_APACK (WS_ZSQ + N_VEC * 4)                    // f16 frag-order z
#define WS_BPACK (WS_APACK + (size_t)N_VEC * 256 * 2)    // f16 frag-order cb
// Bp padded +64KB: pipelined reload reads one step (32KB) past the end
#define WS_RFIN (WS_BPACK + (size_t)K_CODES * 256 * 2 + 65536)
#define WS_ZT (WS_RFIN + (size_t)N_VEC * 8)              // f32 z^T [N_VEC][D]
#define WS_NEED_ZT (WS_ZT + (size_t)N_VEC * D * 4)
#define WS_S1F WS_NEED_ZT                                // f32[N_VEC] coarse min
#define WS_CANDN (WS_S1F + (size_t)N_VEC * 4)            // u32[N_VEC]
#define WS_CANDL (WS_CANDN + (size_t)N_VEC * 4)          // u16[N_VEC][CSTRIDE]
#define WS_LISTB (WS_CANDL + (size_t)N_VEC * CSTRIDE * 2)
#define WS_NEED_CAND (WS_LISTB + (size_t)N_VEC * 4)

// prep fusion block regions
#define PREP_PZ 4096    // pack_z2: 1M frag-slots / 256
#define PREP_PCB 512    // pack_cb2: 128K frag-slots / 256
#define PREP_ESQ 1024
#define PREP_ZSQ 128
#define PREP_BLOCKS (PREP_PZ + PREP_PCB + PREP_ESQ + PREP_ZSQ)

__device__ __forceinline__ unsigned long long pack_key(float s, int idx) {
  const unsigned u = __float_as_uint(s);
  const unsigned mk = (u & 0x80000000u) ? ~u : (u | 0x80000000u);
  return ((unsigned long long)mk << 12) | (unsigned long long)(unsigned)idx;
}
__device__ __forceinline__ float key_score(unsigned long long k) {
  const unsigned mk = (unsigned)(k >> 12);
  const unsigned u = (mk & 0x80000000u) ? (mk & 0x7fffffffu) : ~mk;
  return __uint_as_float(u);
}

// opaque identity: result can't be rematerialized -> forces register residency
__device__ __forceinline__ void pin_frag(f16x8& v) {
  asm volatile("" : "+v"(v));
}

// ---- e_sq body: fp32-squared terms, f64 accumulate, f32 round (frozen) -----
__device__ void esq_body(int bx, const float* __restrict__ cb,
                         float* __restrict__ esq) {
  const int lane = threadIdx.x & 63;
  const int k = bx * 4 + (threadIdx.x >> 6);
  const float* row = cb + (size_t)k * D;
  double s = 0.;
#pragma unroll
  for (int j = 0; j < 4; ++j) {
    const float v = row[lane + 64 * j];
    s += (double)__fmul_rn(v, v);
  }
#pragma unroll
  for (int off = 32; off > 0; off >>= 1) s += __shfl_down(s, off, 64);
  if (lane == 0) esq[k] = (float)s;
}

// ---- z_sq body (frozen: deterministic per-position order) ------------------
__device__ void zsq_body(int bx, const float* __restrict__ z,
                         float* __restrict__ zsq) {
  const int n = bx * 256 + threadIdx.x;
  const int b = n >> 10;
  const int hw = n & 1023;
  const float* p = z + ((size_t)b << 18) + hw;
  double a0 = 0., a1 = 0., a2 = 0., a3 = 0.;
  for (int c = 0; c < D; c += 4) {
    const float v0 = p[(size_t)(c + 0) << 10];
    const float v1 = p[(size_t)(c + 1) << 10];
    const float v2 = p[(size_t)(c + 2) << 10];
    const float v3 = p[(size_t)(c + 3) << 10];
    a0 += (double)__fmul_rn(v0, v0);
    a1 += (double)__fmul_rn(v1, v1);
    a2 += (double)__fmul_rn(v2, v2);
    a3 += (double)__fmul_rn(v3, v3);
  }
  zsq[n] = (float)((a0 + a1) + (a2 + a3));
}

// ---- pack z -> MFMA-fragment order (+ f32 transpose zT) --------------------
__device__ void pack_z2_body(int bx, const float* __restrict__ z,
                             _Float16* __restrict__ Ap,
                             float* __restrict__ zT) {
  const int t = bx * 256 + threadIdx.x;   // [0, 1048576)
  const int lane = t & 63;
  const int fid = t >> 6;                 // [0, 16384)
  const int ks = fid & 7;
  const int grp = fid >> 3;               // 16-row group
  const int n = grp * 16 + (lane & 15);
  const int d = ks * 32 + ((lane >> 4) << 3);
  const int b = n >> 10, hw = n & 1023;
  const float* p = z + ((size_t)b << 18) + ((size_t)d << 10) + hw;
  float v[8];
  f16x8 H;
#pragma unroll
  for (int j = 0; j < 8; ++j) {
    v[j] = p[(size_t)j << 10];
    H[j] = (_Float16)v[j];
  }
  *(f16x8*)(Ap + (size_t)t * 8) = H;
  if (zT) {  // same float values, transposed layout -> coalesced reads later
    float4* o = (float4*)(zT + (size_t)n * D + d);
    o[0] = make_float4(v[0], v[1], v[2], v[3]);
    o[1] = make_float4(v[4], v[5], v[6], v[7]);
  }
}

// ---- pack cb -> MFMA-fragment order, f16(256*e) ----------------------------
__device__ void pack_cb2_body(int bx, const float* __restrict__ cb,
                              _Float16* __restrict__ Bp) {
  const int t = bx * 256 + threadIdx.x;   // [0, 131072)
  const int lane = t & 63;
  const int fid = t >> 6;                 // [0, 2048)
  const int ks = fid & 7;
  const int grp = fid >> 3;               // [0, 256)
  const int k = grp * 16 + (lane & 15);
  const int d = ks * 32 + ((lane >> 4) << 3);
  const float* p = cb + (size_t)k * D + d;
  f16x8 H;
#pragma unroll
  for (int j = 0; j < 8; ++j) H[j] = (_Float16)(p[j] * 256.f);
  *(f16x8*)(Bp + (size_t)t * 8) = H;
}

// ---- fused prep ------------------------------------------------------------
__global__ __launch_bounds__(256) void prep_kernel(
    const float* __restrict__ z, const float* __restrict__ cb,
    float* __restrict__ esq, float* __restrict__ zsq,
    _Float16* __restrict__ Ap, _Float16* __restrict__ Bp,
    float* __restrict__ zT) {
  const int b = blockIdx.x;
  if (b < PREP_PZ) {
    pack_z2_body(b, z, Ap, zT);
  } else if (b < PREP_PZ + PREP_PCB) {
    pack_cb2_body(b - PREP_PZ, cb, Bp);
  } else if (b < PREP_PZ + PREP_PCB + PREP_ESQ) {
    esq_body(b - PREP_PZ - PREP_PCB, cb, esq);
  } else {
    zsq_body(b - PREP_PZ - PREP_PCB - PREP_ESQ, z, zsq);
  }
}

// ---- barrier-free MFMA distance + top-2 (R5-exact fold) --------------------
// Proven-best core: 256 blocks x 128 n-rows, 8 waves (wn x wc), A pinned in
// VGPRs (a[4][8]), B single 8-frag buffer with in-cluster reload, cheap
// top-2 fold (R6/R7/R8 all showed extra per-score work costs ~7us/VALU-op).
// NEW (cert mode): epilogue stores s1f[n] = coarse min (plain store, free);
// candidate COLLECTION moved to the tiny certify_kernel (flagged rows only).
__global__ __launch_bounds__(512, 2) void dist2_kernel(
    const _Float16* __restrict__ Ap, const _Float16* __restrict__ Bp,
    const float* __restrict__ esq, int* __restrict__ idx,
    int* __restrict__ list, unsigned int* __restrict__ count,
    unsigned long long* __restrict__ rfin, float* __restrict__ s1f,
    int* __restrict__ listB, unsigned int* __restrict__ count2) {
  __shared__ unsigned long long mb[128][4][2];  // 8 KB epilogue merge buffer
  const int tid = threadIdx.x;
  const int lane = tid & 63;
  const int w = tid >> 6;
  const int wn = w >> 2;   // n-group  (0..1)
  const int wc = w & 3;    // code-col (0..3)
  const int n0 = blockIdx.x * 128;

  // A frags: this wave's 64 n-rows x full K=256 -> 32 x f16x8 = 128 VGPRs
  f16x8 a[4][8];
  {
    const _Float16* ab =
        Ap + (size_t)((n0 + wn * 64) >> 4) * 4096 + (size_t)lane * 8;
#pragma unroll
    for (int ni = 0; ni < 4; ++ni)
#pragma unroll
      for (int ks = 0; ks < 8; ++ks) {
        a[ni][ks] = *(const f16x8*)(ab + (size_t)(ni * 8 + ks) * 512);
        pin_frag(a[ni][ks]);
      }
  }

  float s1[4], s2[4];
  int i1[4];
#pragma unroll
  for (int ni = 0; ni < 4; ++ni) {
    s1[ni] = 3.4e38f;
    s2[ni] = 3.4e38f;
    i1[ni] = 0;
  }

  const _Float16* bbase = Bp + (size_t)wc * 4096 + (size_t)lane * 8;
  const int crow = wc * 16 + ((lane >> 4) << 2);  // this lane's D-frag row base
  const f32x4 z4 = (f32x4)0.f;

  f16x8 b[8];
#pragma unroll
  for (int ks = 0; ks < 8; ++ks)
    b[ks] = *(const f16x8*)(bbase + (size_t)ks * 512);

  for (int t = 0; t < 64; ++t) {
    const float4 e4 = *(const float4*)(esq + t * 64 + crow);
    f32x4 acc0, acc1, acc2, acc3;
    __builtin_amdgcn_s_setprio(1);
#pragma unroll
    for (int ks = 0; ks < 8; ++ks) {
      acc0 = __builtin_amdgcn_mfma_f32_16x16x32_f16(b[ks], a[0][ks],
                                                    ks ? acc0 : z4, 0, 0, 0);
      acc1 = __builtin_amdgcn_mfma_f32_16x16x32_f16(b[ks], a[1][ks],
                                                    ks ? acc1 : z4, 0, 0, 0);
      acc2 = __builtin_amdgcn_mfma_f32_16x16x32_f16(b[ks], a[2][ks],
                                                    ks ? acc2 : z4, 0, 0, 0);
      acc3 = __builtin_amdgcn_mfma_f32_16x16x32_f16(b[ks], a[3][ks],
                                                    ks ? acc3 : z4, 0, 0, 0);
      // reload for step t+1 (t=63 reads the Bp pad; values unused)
      b[ks] = *(const f16x8*)(bbase + (size_t)(t + 1) * 16384 + ks * 512);
    }
    __builtin_amdgcn_s_setprio(0);
    const int cb0 = t * 64 + crow;
    const float ev[4] = {e4.x, e4.y, e4.z, e4.w};
    f32x4 accv[4] = {acc0, acc1, acc2, acc3};
#pragma unroll
    for (int r = 0; r < 4; ++r) {
      const int code = cb0 + r;
#pragma unroll
      for (int ni = 0; ni < 4; ++ni) {
        const float s = fmaf(accv[ni][r], -0.0078125f, ev[r]);
        s2[ni] = fminf(fmaxf(s, s1[ni]), s2[ni]);
        if (s < s1[ni]) i1[ni] = code;
        s1[ni] = fminf(s1[ni], s);
      }
    }
  }

  // cross-quad merge: lanes l, l^16, l^32, l^48 share n (= output col)
  unsigned long long k1[4], k2[4];
#pragma unroll
  for (int ni = 0; ni < 4; ++ni) {
    float a1 = s1[ni], a2 = s2[ni];
    int ai1 = i1[ni];
#pragma unroll
    for (int m = 16; m <= 32; m <<= 1) {
      const float bv1 = __shfl_xor(a1, m, 64);
      const int bi1 = __shfl_xor(ai1, m, 64);
      const float bv2 = __shfl_xor(a2, m, 64);
      const float hi = fmaxf(a1, bv1);
      const bool take = (bv1 < a1) || (bv1 == a1 && bi1 < ai1);
      if (take) ai1 = bi1;
      a1 = fminf(a1, bv1);
      a2 = fminf(fminf(a2, bv2), hi);
    }
    k1[ni] = pack_key(a1, ai1);
    k2[ni] = pack_key(a2, 0);
  }
  if (lane < 16) {
#pragma unroll
    for (int ni = 0; ni < 4; ++ni) {
      const int nl = wn * 64 + ni * 16 + lane;
      mb[nl][wc][0] = k1[ni];
      mb[nl][wc][1] = k2[ni];
    }
  }
  __syncthreads();
  // finalize: top-2 over the 4 wc pairs, write idx + s1f + flag + routing
  if (tid < 128) {
    unsigned long long m1 = ~0ull, m2 = ~0ull;
#pragma unroll
    for (int s = 0; s < 4; ++s) {
      const unsigned long long c1 = mb[tid][s][0];
      const unsigned long long c2 = mb[tid][s][1];
      if (c1 < m1) {
        m2 = m1;
        m1 = c1;
      } else if (c1 < m2) {
        m2 = c1;
      }
      if (c2 < m2) m2 = c2;  // c2 >= c1 >= m1, only competes for m2
    }
    const int n = n0 + tid;
    idx[n] = (int)(m1 & 0xFFFULL);
    const float sc0 = key_score(m1);
    if (s1f) s1f[n] = sc0;
    const bool flag = key_score(m2) - sc0 < WINDOW;
    rfin[n] = flag ? ~0ull : 0ull;
    if (flag) {
      if (s1f) {  // cert mode: certify_kernel + rescanB consume list
        const unsigned pos = atomicAdd(count, 1u);
        if (pos < N_VEC) list[pos] = n;
      } else {    // no-cert fallback: full-scan rescan consumes listB
        const unsigned p2 = atomicAdd(count2, 1u);
        if (p2 < N_VEC) listB[p2] = n;
      }
    }
  }
}

// ---- certify: recompute coarse scores for FLAGGED rows only; collect -------
// ~1/25 of dist2's MFMA work (tiles of 32 flagged rows x all 4096 codes).
// A-frag gather equals dist2's contiguous-group address for each row
// ((n>>4)*4096 + ks*512 + (lane>>4)*128 + (n&15)*8 == base + lane*8 for
// contiguous groups), same ks-order MFMA chain, same fmaf -> scores are
// BIT-IDENTICAL to dist2's. Append code when s < s1f[n]+1.5W (LDS, rare).
// SOUNDNESS (same invariant as R7/R8, shipped+passed twice): any code that
// can win or tie exactly has coarse <= s1+W < threshold -> always captured;
// capacity overflow (>CAP within 1.5W) -> full-scan fallback via listB.
__global__ __launch_bounds__(256) void certify_kernel(
    const _Float16* __restrict__ Ap, const _Float16* __restrict__ Bp,
    const float* __restrict__ esq, const float* __restrict__ s1f,
    const int* __restrict__ list, const unsigned int* __restrict__ count,
    unsigned int* __restrict__ candn, unsigned short* __restrict__ candl,
    int* __restrict__ listB, unsigned int* __restrict__ count2) {
  if (!candn) return;
  __shared__ unsigned int lcnt[32];
  __shared__ unsigned int lcodes[32][CAP];
  unsigned int cN = *count;
  if (cN > N_VEC) cN = N_VEC;
  if (cN == 0) return;
  const int tid = threadIdx.x;
  const int lane = tid & 63;
  const int wc = tid >> 6;   // 0..3: code-column
  const int l16 = lane & 15;
  const int quad = lane >> 4;
  const unsigned tiles = (cN + 31) / 32;
  const f32x4 z4 = (f32x4)0.f;
  for (unsigned tile = blockIdx.x; tile < tiles; tile += gridDim.x) {
    __syncthreads();  // protect LDS reuse across grid-stride iterations
    if (tid < 32) lcnt[tid] = 0;
    __syncthreads();
    float thrv[2];
    f16x8 af[2][8];
#pragma unroll
    for (int ni = 0; ni < 2; ++ni) {
      unsigned r = tile * 32 + ni * 16 + l16;
      if (r >= cN) r = cN - 1;  // dup-pad rows: appends discarded at write-out
      const int n = list[r];
      thrv[ni] = s1f[n] + WINDOW_C;
      const _Float16* ab = Ap + (size_t)(n >> 4) * 4096 +
                           (size_t)quad * 128 + (size_t)(n & 15) * 8;
#pragma unroll
      for (int ks = 0; ks < 8; ++ks) {
        af[ni][ks] = *(const f16x8*)(ab + (size_t)ks * 512);
        pin_frag(af[ni][ks]);
      }
    }
    const _Float16* bbase = Bp + (size_t)wc * 4096 + (size_t)lane * 8;
    for (int t = 0; t < 64; ++t) {
      const int cb0 = t * 64 + wc * 16 + quad * 4;
      const float4 e4 = *(const float4*)(esq + cb0);
      f16x8 bf[8];
#pragma unroll
      for (int ks = 0; ks < 8; ++ks)
        bf[ks] = *(const f16x8*)(bbase + (size_t)t * 16384 + ks * 512);
      f32x4 acc0, acc1;
#pragma unroll
      for (int ks = 0; ks < 8; ++ks) {
        acc0 = __builtin_amdgcn_mfma_f32_16x16x32_f16(bf[ks], af[0][ks],
                                                      ks ? acc0 : z4, 0, 0, 0);
        acc1 = __builtin_amdgcn_mfma_f32_16x16x32_f16(bf[ks], af[1][ks],
                                                      ks ? acc1 : z4, 0, 0, 0);
      }
      const float ev[4] = {e4.x, e4.y, e4.z, e4.w};
#pragma unroll
      for (int r = 0; r < 4; ++r) {
        const float sA = fmaf(acc0[r], -0.0078125f, ev[r]);
        const float sB = fmaf(acc1[r], -0.0078125f, ev[r]);
        if (sA < thrv[0]) {  // rare (few codes/position inside 1.5W)
          const unsigned u = atomicAdd(&lcnt[l16], 1u);
          if (u < CAP) lcodes[l16][u] = (unsigned)(cb0 + r);
        }
        if (sB < thrv[1]) {
          const unsigned u = atomicAdd(&lcnt[16 + l16], 1u);
          if (u < CAP) lcodes[16 + l16][u] = (unsigned)(cb0 + r);
        }
      }
    }
    __syncthreads();
    if (tid < 32) {
      const unsigned r = tile * 32 + tid;
      if (r < cN) {  // dup-pad columns never write (unique owner per n)
        const int n = list[r];
        const unsigned c = lcnt[tid];
        if (c <= CAP) {
          candn[n] = c;
          for (unsigned u = 0; u < c; ++u)
            candl[(size_t)n * CSTRIDE + u] = (unsigned short)lcodes[tid][u];
        } else {
          candn[n] = 0xFFFFFFFFu;
          const unsigned p = atomicAdd(count2, 1u);
          if (p < N_VEC) listB[p] = n;
        }
      }
    }
  }
}

// ---- rescanB: exact f64 on the collected candidates (frozen chain) ---------
// 8 lanes per position, candidates strided; dot is SERIAL c=0..255 f64 fma
// in x,y,z,w order; d = fl(fl(zsq - fl(2*(float)dot)) + esq[k]); atomicMin
// on packed key (order-independent; ties -> lowest k).
__global__ __launch_bounds__(256) void rescanB_kernel(
    const float* __restrict__ zT, const float* __restrict__ cb,
    const float* __restrict__ esq, const float* __restrict__ zsq,
    const int* __restrict__ list, const unsigned int* __restrict__ count,
    const unsigned int* __restrict__ candn,
    const unsigned short* __restrict__ candl,
    unsigned long long* __restrict__ rfin) {
  if (!candn) return;
  unsigned int cN = *count;
  if (cN > N_VEC) cN = N_VEC;
  const int tid = threadIdx.x;
  const int j8 = tid & 7;
  for (unsigned i = blockIdx.x * 32 + (tid >> 3); i < cN;
       i += gridDim.x * 32) {
    const int n = list[i];
    const unsigned c = candn[n];
    if (c > CAP) continue;  // overflow -> full-scan fallback handles it
    unsigned long long best = ~0ull;
    for (unsigned jj = j8; jj < c; jj += 8) {
      const int k = candl[(size_t)n * CSTRIDE + jj];
      const float* zr = zT + (size_t)n * D;
      const float* row = cb + (size_t)k * D;
      double a = 0.;
      for (int cc = 0; cc < D; cc += 4) {
        const float4 zf = *(const float4*)(zr + cc);
        const float4 r4 = *(const float4*)(row + cc);
        a = fma((double)zf.x, (double)r4.x, a);
        a = fma((double)zf.y, (double)r4.y, a);
        a = fma((double)zf.z, (double)r4.z, a);
        a = fma((double)zf.w, (double)r4.w, a);
      }
      const float d =
          __fadd_rn(__fsub_rn(zsq[n], __fmul_rn(2.0f, (float)a)), esq[k]);
      best = min(best, pack_key(d, k));
    }
    best = min(best, __shfl_xor(best, 1, 64));
    best = min(best, __shfl_xor(best, 2, 64));
    best = min(best, __shfl_xor(best, 4, 64));
    if (j8 == 0) atomicMin(rfin + n, best);
  }
}

// ---- rescan (full-scan fallback for overflow positions; frozen) ------------
__global__ __launch_bounds__(256) void rescan_kernel(
    const float* __restrict__ z, const float* __restrict__ zT,
    const float* __restrict__ cb, const float* __restrict__ esq,
    const float* __restrict__ zsq, const int* __restrict__ list,
    const unsigned int* __restrict__ count,
    unsigned long long* __restrict__ rfin) {
  __shared__ double zrow[RG][D];
  __shared__ int nloc[RG];
  __shared__ float zsv[RG];
  const int tid = threadIdx.x;
  const int lane = tid & 63;
  unsigned int cnt = *count;
  if (cnt > N_VEC) cnt = N_VEC;
  const unsigned G = (cnt + RG - 1) / RG;
  const unsigned nitems = G * (K_CODES / RSLICE);
  for (unsigned item = blockIdx.x; item < nitems; item += gridDim.x) {
    const unsigned g = item >> 4;
    const int s = item & 15;
    __syncthreads();
    if (tid < RG) {
      const unsigned r = g * RG + tid;
      const int n = (r < cnt) ? list[r] : list[cnt - 1];  // dup-pad: idempotent
      nloc[tid] = n;
      zsv[tid] = zsq[n];
    }
    __syncthreads();
    if (zT) {
      for (int i = tid; i < RG * D; i += 256) {
        const int p = i >> 8, c = i & 255;
        zrow[p][c] = (double)zT[(size_t)nloc[p] * D + c];
      }
    } else {
      for (int i = tid; i < RG * D; i += 256) {
        const int p = i >> 8, c = i & 255;
        const int n = nloc[p];
        const int b = n >> 10, hw = n & 1023;
        zrow[p][c] = (double)z[((size_t)b << 18) + ((size_t)c << 10) + hw];
      }
    }
    __syncthreads();
    const int k = s * RSLICE + tid;
    const float* row = cb + (size_t)k * D;
    double acc[RG];
#pragma unroll
    for (int p = 0; p < RG; ++p) acc[p] = 0.;
    for (int c = 0; c < D; c += 4) {
      const float4 r4 = *(const float4*)(row + c);
      const double rx = (double)r4.x, ry = (double)r4.y;
      const double rz = (double)r4.z, rw = (double)r4.w;
#pragma unroll
      for (int p = 0; p < RG; ++p) {
        const double2 za = *(const double2*)&zrow[p][c];
        const double2 zb = *(const double2*)&zrow[p][c + 2];
        double a = acc[p];
        a = fma(za.x, rx, a);
        a = fma(za.y, ry, a);
        a = fma(zb.x, rz, a);
        a = fma(zb.y, rw, a);
        acc[p] = a;
      }
    }
    const float ek = esq[k];
    unsigned long long best[RG];
#pragma unroll
    for (int p = 0; p < RG; ++p) {
      const float dotf = (float)acc[p];
      const float d = __fadd_rn(__fsub_rn(zsv[p], __fmul_rn(2.0f, dotf)), ek);
      best[p] = pack_key(d, k);
    }
#pragma unroll
    for (int p = 0; p < RG; ++p) {
#pragma unroll
      for (int off = 32; off > 0; off >>= 1)
        best[p] = min(best[p], __shfl_down(best[p], off, 64));
    }
    if (lane == 0) {
#pragma unroll
      for (int p = 0; p < RG; ++p) atomicMin(rfin + nloc[p], best[p]);
    }
  }
}

// ---- gather z_q + indices + loss (cb reads float4-ized) --------------------
__global__ __launch_bounds__(256) void gather_kernel(
    const float* __restrict__ z, const float* __restrict__ cb,
    const int* __restrict__ idxarr, const unsigned long long* __restrict__ rfin,
    float* __restrict__ out, float* __restrict__ loss_acc,
    unsigned int* __restrict__ done) {
  const int tid = threadIdx.x;
  const int n0 = blockIdx.x * 64;
  const int hwl = tid & 63;
  const int cq = tid >> 6;  // c block [cq*64, cq*64+64)
  const int n = n0 + hwl;
  const int b = n >> 10;
  const int hw = n & 1023;
  const unsigned long long rf = rfin[n];
  const int idx = rf ? (int)(rf & 0xFFFULL) : idxarr[n];
  if (tid < 64) out[(size_t)N_ELEM + 1 + n] = (float)idx;
  const float* crow = cb + (size_t)idx * D;
  const size_t obase = ((size_t)b << 18) + hw;
  float part = 0.f;
#pragma unroll
  for (int j = 0; j < 16; ++j) {
    const int c = cq * 64 + j * 4;
    const float4 v4 = *(const float4*)(crow + c);
    const size_t o = obase + ((size_t)c << 10);
    const float d0 = v4.x - z[o];
    const float d1 = v4.y - z[o + 1024];
    const float d2 = v4.z - z[o + 2048];
    const float d3 = v4.w - z[o + 3072];
    out[o] = v4.x;
    out[o + 1024] = v4.y;
    out[o + 2048] = v4.z;
    out[o + 3072] = v4.w;
    part = fmaf(d0, d0, part);
    part = fmaf(d1, d1, part);
    part = fmaf(d2, d2, part);
    part = fmaf(d3, d3, part);
  }
#pragma unroll
  for (int off = 32; off > 0; off >>= 1) part += __shfl_down(part, off, 64);
  __shared__ float red[4];
  if ((tid & 63) == 0) red[tid >> 6] = part;
  __syncthreads();
  if (tid == 0) {
    atomicAdd(loss_acc, red[0] + red[1] + red[2] + red[3]);
    __threadfence();
    const unsigned old = atomicAdd(done, 1u);
    if (old == gridDim.x - 1) {
      const float total = atomicAdd(loss_acc, 0.0f);
      out[N_ELEM] = 1.25f * total * (1.0f / (float)N_ELEM);
    }
  }
}

extern "C" void kernel_launch(void* const* d_in, const int* in_sizes, int n_in,
                              void* d_out, int out_size, void* d_ws,
                              size_t ws_size, hipStream_t stream) {
  const float* z = (const float*)d_in[0];
  const float* cb = (const float*)d_in[1];
  float* out = (float*)d_out;
  char* ws = (char*)d_ws;
  float* loss_acc = (float*)(ws + WS_LOSS);
  unsigned int* count = (unsigned int*)(ws + WS_COUNT);
  unsigned int* done = (unsigned int*)(ws + WS_DONE);
  unsigned int* count2 = (unsigned int*)(ws + WS_COUNT2);
  int* idx = (int*)(ws + WS_IDX);
  int* list = (int*)(ws + WS_LIST);
  float* esq = (float*)(ws + WS_ESQ);
  float* zsq = (float*)(ws + WS_ZSQ);
  _Float16* Ap = (_Float16*)(ws + WS_APACK);
  _Float16* Bp = (_Float16*)(ws + WS_BPACK);
  unsigned long long* rfin = (unsigned long long*)(ws + WS_RFIN);
  float* zT = (ws_size >= WS_NEED_ZT) ? (float*)(ws + WS_ZT) : nullptr;
  const bool canduse = (ws_size >= WS_NEED_CAND) && (zT != nullptr);
  float* s1f = canduse ? (float*)(ws + WS_S1F) : nullptr;
  unsigned int* candn = canduse ? (unsigned int*)(ws + WS_CANDN) : nullptr;
  unsigned short* candl = canduse ? (unsigned short*)(ws + WS_CANDL) : nullptr;
  int* listB = canduse ? (int*)(ws + WS_LISTB) : list;

  hipMemsetAsync(ws, 0, 256, stream);
  prep_kernel<<<PREP_BLOCKS, 256, 0, stream>>>(z, cb, esq, zsq, Ap, Bp, zT);
  dist2_kernel<<<N_VEC / 128, 512, 0, stream>>>(Ap, Bp, esq, idx, list, count,
                                                rfin, s1f, listB, count2);
  certify_kernel<<<128, 256, 0, stream>>>(Ap, Bp, esq, s1f, list, count, candn,
                                          candl, listB, count2);
  rescanB_kernel<<<256, 256, 0, stream>>>(zT, cb, esq, zsq, list, count, candn,
                                          candl, rfin);
  rescan_kernel<<<2048, 256, 0, stream>>>(z, zT, cb, esq, zsq, listB, count2,
                                          rfin);
  gather_kernel<<<N_VEC / 64, 256, 0, stream>>>(z, cb, idx, rfin, out,
                                                loss_acc, done);
}

// Round 10
// 248.991 us; speedup vs baseline: 1.1976x; 1.1976x over previous
//
#include <hip/hip_runtime.h>

#define K_CODES 4096
#define D 256
#define N_VEC 32768
#define N_ELEM 8388608   // 32*256*32*32
#define WINDOW 3.5e-4f
#define WINDOW_C 5.25e-4f  // certify capture window (1.5x WINDOW > W margin)
#define CAP 14             // candidate capacity per position (certify)
#define CSTRIDE 16         // u16 slots per position in candl
#define RG 8               // rescan positions per group (fallback)
#define RSLICE 256         // rescan codes per slice (fallback)

typedef _Float16 f16x8 __attribute__((ext_vector_type(8)));
typedef float f32x4 __attribute__((ext_vector_type(4)));

// ws layout (bytes)
#define WS_LOSS 0
#define WS_COUNT 8
#define WS_DONE 16
#define WS_COUNT2 24
#define WS_IDX 256
#define WS_LIST (WS_IDX + N_VEC * 4)
#define WS_ESQ (WS_LIST + N_VEC * 4)
#define WS_ZSQ (WS_ESQ + K_CODES * 4)
#define WS_APACK (WS_ZSQ + N_VEC * 4)                    // f16 frag-order z
#define WS_BPACK (WS_APACK + (size_t)N_VEC * 256 * 2)    // f16 frag-order cb
// Bp padded +64KB: pipelined reload reads one step (32KB) past the end
#define WS_RFIN (WS_BPACK + (size_t)K_CODES * 256 * 2 + 65536)
#define WS_ZT (WS_RFIN + (size_t)N_VEC * 8)              // f32 z^T [N_VEC][D]
#define WS_NEED_ZT (WS_ZT + (size_t)N_VEC * D * 4)
#define WS_S1F WS_NEED_ZT                                // f32[N_VEC] coarse min
#define WS_CANDN (WS_S1F + (size_t)N_VEC * 4)            // u32[N_VEC]
#define WS_CANDL (WS_CANDN + (size_t)N_VEC * 4)          // u16[N_VEC][CSTRIDE]
#define WS_LISTB (WS_CANDL + (size_t)N_VEC * CSTRIDE * 2)
#define WS_NEED_CAND (WS_LISTB + (size_t)N_VEC * 4)

// prep fusion block regions
#define PREP_PZ 4096    // pack_z2: 1M frag-slots / 256
#define PREP_PCB 512    // pack_cb2: 128K frag-slots / 256
#define PREP_ESQ 1024
#define PREP_ZSQ 128
#define PREP_BLOCKS (PREP_PZ + PREP_PCB + PREP_ESQ + PREP_ZSQ)

__device__ __forceinline__ unsigned long long pack_key(float s, int idx) {
  const unsigned u = __float_as_uint(s);
  const unsigned mk = (u & 0x80000000u) ? ~u : (u | 0x80000000u);
  return ((unsigned long long)mk << 12) | (unsigned long long)(unsigned)idx;
}
__device__ __forceinline__ float key_score(unsigned long long k) {
  const unsigned mk = (unsigned)(k >> 12);
  const unsigned u = (mk & 0x80000000u) ? (mk & 0x7fffffffu) : ~mk;
  return __uint_as_float(u);
}

// opaque identity: result can't be rematerialized -> forces register residency
__device__ __forceinline__ void pin_frag(f16x8& v) {
  asm volatile("" : "+v"(v));
}

// ---- e_sq body: fp32-squared terms, f64 accumulate, f32 round (frozen) -----
__device__ void esq_body(int bx, const float* __restrict__ cb,
                         float* __restrict__ esq) {
  const int lane = threadIdx.x & 63;
  const int k = bx * 4 + (threadIdx.x >> 6);
  const float* row = cb + (size_t)k * D;
  double s = 0.;
#pragma unroll
  for (int j = 0; j < 4; ++j) {
    const float v = row[lane + 64 * j];
    s += (double)__fmul_rn(v, v);
  }
#pragma unroll
  for (int off = 32; off > 0; off >>= 1) s += __shfl_down(s, off, 64);
  if (lane == 0) esq[k] = (float)s;
}

// ---- z_sq body (frozen: deterministic per-position order) ------------------
__device__ void zsq_body(int bx, const float* __restrict__ z,
                         float* __restrict__ zsq) {
  const int n = bx * 256 + threadIdx.x;
  const int b = n >> 10;
  const int hw = n & 1023;
  const float* p = z + ((size_t)b << 18) + hw;
  double a0 = 0., a1 = 0., a2 = 0., a3 = 0.;
  for (int c = 0; c < D; c += 4) {
    const float v0 = p[(size_t)(c + 0) << 10];
    const float v1 = p[(size_t)(c + 1) << 10];
    const float v2 = p[(size_t)(c + 2) << 10];
    const float v3 = p[(size_t)(c + 3) << 10];
    a0 += (double)__fmul_rn(v0, v0);
    a1 += (double)__fmul_rn(v1, v1);
    a2 += (double)__fmul_rn(v2, v2);
    a3 += (double)__fmul_rn(v3, v3);
  }
  zsq[n] = (float)((a0 + a1) + (a2 + a3));
}

// ---- pack z -> MFMA-fragment order (+ f32 transpose zT) --------------------
__device__ void pack_z2_body(int bx, const float* __restrict__ z,
                             _Float16* __restrict__ Ap,
                             float* __restrict__ zT) {
  const int t = bx * 256 + threadIdx.x;   // [0, 1048576)
  const int lane = t & 63;
  const int fid = t >> 6;                 // [0, 16384)
  const int ks = fid & 7;
  const int grp = fid >> 3;               // 16-row group
  const int n = grp * 16 + (lane & 15);
  const int d = ks * 32 + ((lane >> 4) << 3);
  const int b = n >> 10, hw = n & 1023;
  const float* p = z + ((size_t)b << 18) + ((size_t)d << 10) + hw;
  float v[8];
  f16x8 H;
#pragma unroll
  for (int j = 0; j < 8; ++j) {
    v[j] = p[(size_t)j << 10];
    H[j] = (_Float16)v[j];
  }
  *(f16x8*)(Ap + (size_t)t * 8) = H;
  if (zT) {  // same float values, transposed layout -> coalesced reads later
    float4* o = (float4*)(zT + (size_t)n * D + d);
    o[0] = make_float4(v[0], v[1], v[2], v[3]);
    o[1] = make_float4(v[4], v[5], v[6], v[7]);
  }
}

// ---- pack cb -> MFMA-fragment order, f16(256*e) ----------------------------
__device__ void pack_cb2_body(int bx, const float* __restrict__ cb,
                              _Float16* __restrict__ Bp) {
  const int t = bx * 256 + threadIdx.x;   // [0, 131072)
  const int lane = t & 63;
  const int fid = t >> 6;                 // [0, 2048)
  const int ks = fid & 7;
  const int grp = fid >> 3;               // [0, 256)
  const int k = grp * 16 + (lane & 15);
  const int d = ks * 32 + ((lane >> 4) << 3);
  const float* p = cb + (size_t)k * D + d;
  f16x8 H;
#pragma unroll
  for (int j = 0; j < 8; ++j) H[j] = (_Float16)(p[j] * 256.f);
  *(f16x8*)(Bp + (size_t)t * 8) = H;
}

// ---- fused prep ------------------------------------------------------------
__global__ __launch_bounds__(256) void prep_kernel(
    const float* __restrict__ z, const float* __restrict__ cb,
    float* __restrict__ esq, float* __restrict__ zsq,
    _Float16* __restrict__ Ap, _Float16* __restrict__ Bp,
    float* __restrict__ zT) {
  const int b = blockIdx.x;
  if (b < PREP_PZ) {
    pack_z2_body(b, z, Ap, zT);
  } else if (b < PREP_PZ + PREP_PCB) {
    pack_cb2_body(b - PREP_PZ, cb, Bp);
  } else if (b < PREP_PZ + PREP_PCB + PREP_ESQ) {
    esq_body(b - PREP_PZ - PREP_PCB, cb, esq);
  } else {
    zsq_body(b - PREP_PZ - PREP_PCB - PREP_ESQ, z, zsq);
  }
}

// ---- barrier-free MFMA distance + top-2 (R5-exact fold, unchanged) ---------
__global__ __launch_bounds__(512, 2) void dist2_kernel(
    const _Float16* __restrict__ Ap, const _Float16* __restrict__ Bp,
    const float* __restrict__ esq, int* __restrict__ idx,
    int* __restrict__ list, unsigned int* __restrict__ count,
    unsigned long long* __restrict__ rfin, float* __restrict__ s1f,
    int* __restrict__ listB, unsigned int* __restrict__ count2) {
  __shared__ unsigned long long mb[128][4][2];  // 8 KB epilogue merge buffer
  const int tid = threadIdx.x;
  const int lane = tid & 63;
  const int w = tid >> 6;
  const int wn = w >> 2;   // n-group  (0..1)
  const int wc = w & 3;    // code-col (0..3)
  const int n0 = blockIdx.x * 128;

  // A frags: this wave's 64 n-rows x full K=256 -> 32 x f16x8 = 128 VGPRs
  f16x8 a[4][8];
  {
    const _Float16* ab =
        Ap + (size_t)((n0 + wn * 64) >> 4) * 4096 + (size_t)lane * 8;
#pragma unroll
    for (int ni = 0; ni < 4; ++ni)
#pragma unroll
      for (int ks = 0; ks < 8; ++ks) {
        a[ni][ks] = *(const f16x8*)(ab + (size_t)(ni * 8 + ks) * 512);
        pin_frag(a[ni][ks]);
      }
  }

  float s1[4], s2[4];
  int i1[4];
#pragma unroll
  for (int ni = 0; ni < 4; ++ni) {
    s1[ni] = 3.4e38f;
    s2[ni] = 3.4e38f;
    i1[ni] = 0;
  }

  const _Float16* bbase = Bp + (size_t)wc * 4096 + (size_t)lane * 8;
  const int crow = wc * 16 + ((lane >> 4) << 2);  // this lane's D-frag row base
  const f32x4 z4 = (f32x4)0.f;

  f16x8 b[8];
#pragma unroll
  for (int ks = 0; ks < 8; ++ks)
    b[ks] = *(const f16x8*)(bbase + (size_t)ks * 512);

  for (int t = 0; t < 64; ++t) {
    const float4 e4 = *(const float4*)(esq + t * 64 + crow);
    f32x4 acc0, acc1, acc2, acc3;
    __builtin_amdgcn_s_setprio(1);
#pragma unroll
    for (int ks = 0; ks < 8; ++ks) {
      acc0 = __builtin_amdgcn_mfma_f32_16x16x32_f16(b[ks], a[0][ks],
                                                    ks ? acc0 : z4, 0, 0, 0);
      acc1 = __builtin_amdgcn_mfma_f32_16x16x32_f16(b[ks], a[1][ks],
                                                    ks ? acc1 : z4, 0, 0, 0);
      acc2 = __builtin_amdgcn_mfma_f32_16x16x32_f16(b[ks], a[2][ks],
                                                    ks ? acc2 : z4, 0, 0, 0);
      acc3 = __builtin_amdgcn_mfma_f32_16x16x32_f16(b[ks], a[3][ks],
                                                    ks ? acc3 : z4, 0, 0, 0);
      // reload for step t+1 (t=63 reads the Bp pad; values unused)
      b[ks] = *(const f16x8*)(bbase + (size_t)(t + 1) * 16384 + ks * 512);
    }
    __builtin_amdgcn_s_setprio(0);
    const int cb0 = t * 64 + crow;
    const float ev[4] = {e4.x, e4.y, e4.z, e4.w};
    f32x4 accv[4] = {acc0, acc1, acc2, acc3};
#pragma unroll
    for (int r = 0; r < 4; ++r) {
      const int code = cb0 + r;
#pragma unroll
      for (int ni = 0; ni < 4; ++ni) {
        const float s = fmaf(accv[ni][r], -0.0078125f, ev[r]);
        s2[ni] = fminf(fmaxf(s, s1[ni]), s2[ni]);
        if (s < s1[ni]) i1[ni] = code;
        s1[ni] = fminf(s1[ni], s);
      }
    }
  }

  // cross-quad merge: lanes l, l^16, l^32, l^48 share n (= output col)
  unsigned long long k1[4], k2[4];
#pragma unroll
  for (int ni = 0; ni < 4; ++ni) {
    float a1 = s1[ni], a2 = s2[ni];
    int ai1 = i1[ni];
#pragma unroll
    for (int m = 16; m <= 32; m <<= 1) {
      const float bv1 = __shfl_xor(a1, m, 64);
      const int bi1 = __shfl_xor(ai1, m, 64);
      const float bv2 = __shfl_xor(a2, m, 64);
      const float hi = fmaxf(a1, bv1);
      const bool take = (bv1 < a1) || (bv1 == a1 && bi1 < ai1);
      if (take) ai1 = bi1;
      a1 = fminf(a1, bv1);
      a2 = fminf(fminf(a2, bv2), hi);
    }
    k1[ni] = pack_key(a1, ai1);
    k2[ni] = pack_key(a2, 0);
  }
  if (lane < 16) {
#pragma unroll
    for (int ni = 0; ni < 4; ++ni) {
      const int nl = wn * 64 + ni * 16 + lane;
      mb[nl][wc][0] = k1[ni];
      mb[nl][wc][1] = k2[ni];
    }
  }
  __syncthreads();
  // finalize: top-2 over the 4 wc pairs, write idx + s1f + flag + routing
  if (tid < 128) {
    unsigned long long m1 = ~0ull, m2 = ~0ull;
#pragma unroll
    for (int s = 0; s < 4; ++s) {
      const unsigned long long c1 = mb[tid][s][0];
      const unsigned long long c2 = mb[tid][s][1];
      if (c1 < m1) {
        m2 = m1;
        m1 = c1;
      } else if (c1 < m2) {
        m2 = c1;
      }
      if (c2 < m2) m2 = c2;  // c2 >= c1 >= m1, only competes for m2
    }
    const int n = n0 + tid;
    idx[n] = (int)(m1 & 0xFFFULL);
    const float sc0 = key_score(m1);
    if (s1f) s1f[n] = sc0;
    const bool flag = key_score(m2) - sc0 < WINDOW;
    rfin[n] = flag ? ~0ull : 0ull;
    if (flag) {
      if (s1f) {  // cert mode: certify_kernel + rescanB consume list
        const unsigned pos = atomicAdd(count, 1u);
        if (pos < N_VEC) list[pos] = n;
      } else {    // no-cert fallback: full-scan rescan consumes listB
        const unsigned p2 = atomicAdd(count2, 1u);
        if (p2 < N_VEC) listB[p2] = n;
      }
    }
  }
}

// ---- certify v2: wave-per-(16-pos tile x 256-code slice) -------------------
// R9's certify was latency-dead: ~78 blocks, zero overlap, 163us. v2 fans the
// work across BOTH axes: item = (pos-tile, 16-group code slice) -> ~cN items,
// 2048 single-wave blocks, each item = 16 x {8 bf loads + 8 MFMA + test}.
// MFMA chain (same frags, same ks order, same fmaf) is BIT-IDENTICAL to
// dist2's scores. Appends are GLOBAL atomics but rare (~3/position TOTAL):
// this is NOT R6 - the test is branchless-cheap, the taken path ~10K times
// grid-wide. Slices disjoint -> no duplicate appends; candn counts via
// atomic ticket; overflow (>CAP) routed to full-scan fallback by rescanB.
// SOUNDNESS: unchanged R8 invariant - any exact winner/tie has
// coarse <= s1f+W < s1f+WINDOW_C -> captured (winner itself: s1f < thr).
__global__ __launch_bounds__(64) void certify_kernel(
    const _Float16* __restrict__ Ap, const _Float16* __restrict__ Bp,
    const float* __restrict__ esq, const float* __restrict__ s1f,
    const int* __restrict__ list, const unsigned int* __restrict__ count,
    unsigned int* __restrict__ candn, unsigned short* __restrict__ candl) {
  if (!candn) return;
  unsigned int cN = *count;
  if (cN > N_VEC) cN = N_VEC;
  if (cN == 0) return;
  const int lane = threadIdx.x & 63;
  const int l16 = lane & 15;
  const int quad = lane >> 4;
  const unsigned ptiles = (cN + 15) / 16;
  const unsigned items = ptiles * 16;  // 16 slices x 16 groups = 4096 codes
  const f32x4 z4 = (f32x4)0.f;
  for (unsigned item = blockIdx.x; item < items; item += gridDim.x) {
    const unsigned pt = item >> 4;
    const unsigned sl = item & 15;     // code groups [sl*16, sl*16+16)
    unsigned r = pt * 16 + l16;
    const bool valid = (r < cN);
    if (!valid) r = cN - 1;            // dup-pad; appends masked by valid
    const int n = list[r];
    const float thr = s1f[n] + WINDOW_C;
    // A frags for row n (same address algebra as dist2's contiguous load)
    f16x8 af[8];
    const _Float16* ab = Ap + (size_t)(n >> 4) * 4096 + (size_t)quad * 128 +
                         (size_t)(n & 15) * 8;
#pragma unroll
    for (int ks = 0; ks < 8; ++ks) {
      af[ks] = *(const f16x8*)(ab + (size_t)ks * 512);
      pin_frag(af[ks]);
    }
#pragma unroll 2
    for (int g = 0; g < 16; ++g) {
      const int grp = sl * 16 + g;     // 16 codes
      const _Float16* bb = Bp + (size_t)grp * 4096 + (size_t)lane * 8;
      f16x8 bf[8];
#pragma unroll
      for (int ks = 0; ks < 8; ++ks)
        bf[ks] = *(const f16x8*)(bb + (size_t)ks * 512);
      f32x4 acc;
#pragma unroll
      for (int ks = 0; ks < 8; ++ks)
        acc = __builtin_amdgcn_mfma_f32_16x16x32_f16(bf[ks], af[ks],
                                                     ks ? acc : z4, 0, 0, 0);
      const int cb0 = grp * 16 + quad * 4;
      const float4 e4 = *(const float4*)(esq + cb0);
      const float ev[4] = {e4.x, e4.y, e4.z, e4.w};
#pragma unroll
      for (int rr = 0; rr < 4; ++rr) {
        const float s = fmaf(acc[rr], -0.0078125f, ev[rr]);
        if (valid && s < thr) {  // rare: ~3 codes/position across ALL slices
          const unsigned u = atomicAdd(&candn[n], 1u);
          if (u < CAP)
            candl[(size_t)n * CSTRIDE + u] = (unsigned short)(cb0 + rr);
        }
      }
    }
  }
}

// ---- rescanB: exact f64 on collected candidates + overflow routing ---------
// 8 lanes per position; dot is SERIAL c=0..255 f64 fma in x,y,z,w order;
// d = fl(fl(zsq - fl(2*(float)dot)) + esq[k]); atomicMin on packed key
// (order-independent; ties -> lowest k). Overflow (candn>CAP) -> listB.
__global__ __launch_bounds__(256) void rescanB_kernel(
    const float* __restrict__ zT, const float* __restrict__ cb,
    const float* __restrict__ esq, const float* __restrict__ zsq,
    const int* __restrict__ list, const unsigned int* __restrict__ count,
    const unsigned int* __restrict__ candn,
    const unsigned short* __restrict__ candl,
    unsigned long long* __restrict__ rfin, int* __restrict__ listB,
    unsigned int* __restrict__ count2) {
  if (!candn) return;
  unsigned int cN = *count;
  if (cN > N_VEC) cN = N_VEC;
  const int tid = threadIdx.x;
  const int j8 = tid & 7;
  for (unsigned i = blockIdx.x * 32 + (tid >> 3); i < cN;
       i += gridDim.x * 32) {
    const int n = list[i];
    const unsigned c = candn[n];
    if (c > CAP) {  // overflow -> full-scan fallback (unique owner per i)
      if (j8 == 0) {
        const unsigned p = atomicAdd(count2, 1u);
        if (p < N_VEC) listB[p] = n;
      }
      continue;
    }
    unsigned long long best = ~0ull;
    for (unsigned jj = j8; jj < c; jj += 8) {
      const int k = candl[(size_t)n * CSTRIDE + jj];
      const float* zr = zT + (size_t)n * D;
      const float* row = cb + (size_t)k * D;
      double a = 0.;
      for (int cc = 0; cc < D; cc += 4) {
        const float4 zf = *(const float4*)(zr + cc);
        const float4 r4 = *(const float4*)(row + cc);
        a = fma((double)zf.x, (double)r4.x, a);
        a = fma((double)zf.y, (double)r4.y, a);
        a = fma((double)zf.z, (double)r4.z, a);
        a = fma((double)zf.w, (double)r4.w, a);
      }
      const float d =
          __fadd_rn(__fsub_rn(zsq[n], __fmul_rn(2.0f, (float)a)), esq[k]);
      best = min(best, pack_key(d, k));
    }
    best = min(best, __shfl_xor(best, 1, 64));
    best = min(best, __shfl_xor(best, 2, 64));
    best = min(best, __shfl_xor(best, 4, 64));
    if (j8 == 0 && best != ~0ull) atomicMin(rfin + n, best);
  }
}

// ---- rescan (full-scan fallback for overflow positions; frozen) ------------
__global__ __launch_bounds__(256) void rescan_kernel(
    const float* __restrict__ z, const float* __restrict__ zT,
    const float* __restrict__ cb, const float* __restrict__ esq,
    const float* __restrict__ zsq, const int* __restrict__ list,
    const unsigned int* __restrict__ count,
    unsigned long long* __restrict__ rfin) {
  __shared__ double zrow[RG][D];
  __shared__ int nloc[RG];
  __shared__ float zsv[RG];
  const int tid = threadIdx.x;
  const int lane = tid & 63;
  unsigned int cnt = *count;
  if (cnt > N_VEC) cnt = N_VEC;
  const unsigned G = (cnt + RG - 1) / RG;
  const unsigned nitems = G * (K_CODES / RSLICE);
  for (unsigned item = blockIdx.x; item < nitems; item += gridDim.x) {
    const unsigned g = item >> 4;
    const int s = item & 15;
    __syncthreads();
    if (tid < RG) {
      const unsigned r = g * RG + tid;
      const int n = (r < cnt) ? list[r] : list[cnt - 1];  // dup-pad: idempotent
      nloc[tid] = n;
      zsv[tid] = zsq[n];
    }
    __syncthreads();
    if (zT) {
      for (int i = tid; i < RG * D; i += 256) {
        const int p = i >> 8, c = i & 255;
        zrow[p][c] = (double)zT[(size_t)nloc[p] * D + c];
      }
    } else {
      for (int i = tid; i < RG * D; i += 256) {
        const int p = i >> 8, c = i & 255;
        const int n = nloc[p];
        const int b = n >> 10, hw = n & 1023;
        zrow[p][c] = (double)z[((size_t)b << 18) + ((size_t)c << 10) + hw];
      }
    }
    __syncthreads();
    const int k = s * RSLICE + tid;
    const float* row = cb + (size_t)k * D;
    double acc[RG];
#pragma unroll
    for (int p = 0; p < RG; ++p) acc[p] = 0.;
    for (int c = 0; c < D; c += 4) {
      const float4 r4 = *(const float4*)(row + c);
      const double rx = (double)r4.x, ry = (double)r4.y;
      const double rz = (double)r4.z, rw = (double)r4.w;
#pragma unroll
      for (int p = 0; p < RG; ++p) {
        const double2 za = *(const double2*)&zrow[p][c];
        const double2 zb = *(const double2*)&zrow[p][c + 2];
        double a = acc[p];
        a = fma(za.x, rx, a);
        a = fma(za.y, ry, a);
        a = fma(zb.x, rz, a);
        a = fma(zb.y, rw, a);
        acc[p] = a;
      }
    }
    const float ek = esq[k];
    unsigned long long best[RG];
#pragma unroll
    for (int p = 0; p < RG; ++p) {
      const float dotf = (float)acc[p];
      const float d = __fadd_rn(__fsub_rn(zsv[p], __fmul_rn(2.0f, dotf)), ek);
      best[p] = pack_key(d, k);
    }
#pragma unroll
    for (int p = 0; p < RG; ++p) {
#pragma unroll
      for (int off = 32; off > 0; off >>= 1)
        best[p] = min(best[p], __shfl_down(best[p], off, 64));
    }
    if (lane == 0) {
#pragma unroll
      for (int p = 0; p < RG; ++p) atomicMin(rfin + nloc[p], best[p]);
    }
  }
}

// ---- gather z_q + indices + loss (cb reads float4-ized) --------------------
__global__ __launch_bounds__(256) void gather_kernel(
    const float* __restrict__ z, const float* __restrict__ cb,
    const int* __restrict__ idxarr, const unsigned long long* __restrict__ rfin,
    float* __restrict__ out, float* __restrict__ loss_acc,
    unsigned int* __restrict__ done) {
  const int tid = threadIdx.x;
  const int n0 = blockIdx.x * 64;
  const int hwl = tid & 63;
  const int cq = tid >> 6;  // c block [cq*64, cq*64+64)
  const int n = n0 + hwl;
  const int b = n >> 10;
  const int hw = n & 1023;
  const unsigned long long rf = rfin[n];
  const int idx = rf ? (int)(rf & 0xFFFULL) : idxarr[n];
  if (tid < 64) out[(size_t)N_ELEM + 1 + n] = (float)idx;
  const float* crow = cb + (size_t)idx * D;
  const size_t obase = ((size_t)b << 18) + hw;
  float part = 0.f;
#pragma unroll
  for (int j = 0; j < 16; ++j) {
    const int c = cq * 64 + j * 4;
    const float4 v4 = *(const float4*)(crow + c);
    const size_t o = obase + ((size_t)c << 10);
    const float d0 = v4.x - z[o];
    const float d1 = v4.y - z[o + 1024];
    const float d2 = v4.z - z[o + 2048];
    const float d3 = v4.w - z[o + 3072];
    out[o] = v4.x;
    out[o + 1024] = v4.y;
    out[o + 2048] = v4.z;
    out[o + 3072] = v4.w;
    part = fmaf(d0, d0, part);
    part = fmaf(d1, d1, part);
    part = fmaf(d2, d2, part);
    part = fmaf(d3, d3, part);
  }
#pragma unroll
  for (int off = 32; off > 0; off >>= 1) part += __shfl_down(part, off, 64);
  __shared__ float red[4];
  if ((tid & 63) == 0) red[tid >> 6] = part;
  __syncthreads();
  if (tid == 0) {
    atomicAdd(loss_acc, red[0] + red[1] + red[2] + red[3]);
    __threadfence();
    const unsigned old = atomicAdd(done, 1u);
    if (old == gridDim.x - 1) {
      const float total = atomicAdd(loss_acc, 0.0f);
      out[N_ELEM] = 1.25f * total * (1.0f / (float)N_ELEM);
    }
  }
}

extern "C" void kernel_launch(void* const* d_in, const int* in_sizes, int n_in,
                              void* d_out, int out_size, void* d_ws,
                              size_t ws_size, hipStream_t stream) {
  const float* z = (const float*)d_in[0];
  const float* cb = (const float*)d_in[1];
  float* out = (float*)d_out;
  char* ws = (char*)d_ws;
  float* loss_acc = (float*)(ws + WS_LOSS);
  unsigned int* count = (unsigned int*)(ws + WS_COUNT);
  unsigned int* done = (unsigned int*)(ws + WS_DONE);
  unsigned int* count2 = (unsigned int*)(ws + WS_COUNT2);
  int* idx = (int*)(ws + WS_IDX);
  int* list = (int*)(ws + WS_LIST);
  float* esq = (float*)(ws + WS_ESQ);
  float* zsq = (float*)(ws + WS_ZSQ);
  _Float16* Ap = (_Float16*)(ws + WS_APACK);
  _Float16* Bp = (_Float16*)(ws + WS_BPACK);
  unsigned long long* rfin = (unsigned long long*)(ws + WS_RFIN);
  float* zT = (ws_size >= WS_NEED_ZT) ? (float*)(ws + WS_ZT) : nullptr;
  const bool canduse = (ws_size >= WS_NEED_CAND) && (zT != nullptr);
  float* s1f = canduse ? (float*)(ws + WS_S1F) : nullptr;
  unsigned int* candn = canduse ? (unsigned int*)(ws + WS_CANDN) : nullptr;
  unsigned short* candl = canduse ? (unsigned short*)(ws + WS_CANDL) : nullptr;
  int* listB = canduse ? (int*)(ws + WS_LISTB) : list;

  hipMemsetAsync(ws, 0, 256, stream);
  if (canduse) hipMemsetAsync(ws + WS_CANDN, 0, (size_t)N_VEC * 4, stream);
  prep_kernel<<<PREP_BLOCKS, 256, 0, stream>>>(z, cb, esq, zsq, Ap, Bp, zT);
  dist2_kernel<<<N_VEC / 128, 512, 0, stream>>>(Ap, Bp, esq, idx, list, count,
                                                rfin, s1f, listB, count2);
  certify_kernel<<<2048, 64, 0, stream>>>(Ap, Bp, esq, s1f, list, count, candn,
                                          candl);
  rescanB_kernel<<<256, 256, 0, stream>>>(zT, cb, esq, zsq, list, count, candn,
                                          candl, rfin, listB, count2);
  rescan_kernel<<<2048, 256, 0, stream>>>(z, zT, cb, esq, zsq, listB, count2,
                                          rfin);
  gather_kernel<<<N_VEC / 64, 256, 0, stream>>>(z, cb, idx, rfin, out,
                                                loss_acc, done);
}